// Round 1
// baseline (409.490 us; speedup 1.0000x reference)
//
#include <hip/hip_runtime.h>

// Interleaver: coords in [0,256)^3, R=2 -> coarse grid 128^3 = 2^21 cells.
// key = (x>>1)<<14 | (y>>1)<<7 | (z>>1)  == lexicographic row order of base,
// so jnp.unique's sorted unique index == exclusive prefix sum of presence[key].

#define CELLS (1u << 21)   // 128^3
#define CHUNK 4096         // cells per scan block (256 thr x 16 elem)

__global__ void fill_coords_kernel(float* out, int n3) {
    int i = blockIdx.x * blockDim.x + threadIdx.x;
    if (i < n3) out[i] = -1.0f;   // fill_value=-1 padding; real rows overwritten later
}

__global__ void mark_cells_kernel(const int* __restrict__ coords,
                                  unsigned* __restrict__ presence, int n) {
    int i = blockIdx.x * blockDim.x + threadIdx.x;
    if (i >= n) return;
    int cx = coords[3 * i], cy = coords[3 * i + 1], cz = coords[3 * i + 2];
    unsigned key = ((unsigned)(cx >> 1) << 14) | ((unsigned)(cy >> 1) << 7) |
                   (unsigned)(cz >> 1);
    presence[key] = 1u;
}

// Per-chunk exclusive scan: 512 blocks x (256 thr x 16 elems) over 2M cells.
__global__ void scan1_kernel(const unsigned* __restrict__ presence,
                             unsigned* __restrict__ rank,
                             unsigned* __restrict__ blockSums) {
    __shared__ unsigned sh[256];
    int t = threadIdx.x;
    unsigned base = blockIdx.x * CHUNK + t * 16;
    unsigned v[16];
#pragma unroll
    for (int j = 0; j < 16; ++j) v[j] = presence[base + j];
    unsigned s = 0;
#pragma unroll
    for (int j = 0; j < 16; ++j) { unsigned x = v[j]; v[j] = s; s += x; }
    unsigned x = s;
    sh[t] = x; __syncthreads();
    for (int d = 1; d < 256; d <<= 1) {
        unsigned y = (t >= d) ? sh[t - d] : 0u;
        __syncthreads();
        x += y; sh[t] = x; __syncthreads();
    }
    unsigned excl = x - s;   // exclusive prefix of this thread within chunk
#pragma unroll
    for (int j = 0; j < 16; ++j) rank[base + j] = v[j] + excl;
    if (t == 255) blockSums[blockIdx.x] = x;   // chunk total
}

// Exclusive scan of the 512 chunk totals, in place.
__global__ void scan2_kernel(unsigned* blockSums) {
    __shared__ unsigned sh[512];
    int t = threadIdx.x;
    unsigned s = blockSums[t];
    unsigned x = s;
    sh[t] = x; __syncthreads();
    for (int d = 1; d < 512; d <<= 1) {
        unsigned y = (t >= d) ? sh[t - d] : 0u;
        __syncthreads();
        x += y; sh[t] = x; __syncthreads();
    }
    blockSums[t] = x - s;   // exclusive
}

// Globalize ranks; present cells write their (sorted) coarse coords as floats.
__global__ void finalize_kernel(const unsigned* __restrict__ presence,
                                unsigned* __restrict__ rank,
                                const unsigned* __restrict__ blockSums,
                                float* __restrict__ coords_out) {
    unsigned i = blockIdx.x * 256 + threadIdx.x;
    unsigned r = rank[i] + blockSums[i >> 12];   // chunk = 4096 = 2^12
    rank[i] = r;
    if (presence[i]) {
        coords_out[3 * r + 0] = (float)(i >> 14);
        coords_out[3 * r + 1] = (float)((i >> 7) & 127u);
        coords_out[3 * r + 2] = (float)(i & 127u);
    }
}

// Duplicate (cell,offset) slots: reference (numpy/XLA sequential scatter) is
// last-write-wins in point order -> the max point index wins.
__global__ void pick_winner_kernel(const int* __restrict__ coords,
                                   const unsigned* __restrict__ rank,
                                   int* __restrict__ winner, int n) {
    int i = blockIdx.x * blockDim.x + threadIdx.x;
    if (i >= n) return;
    int cx = coords[3 * i], cy = coords[3 * i + 1], cz = coords[3 * i + 2];
    unsigned key = ((unsigned)(cx >> 1) << 14) | ((unsigned)(cy >> 1) << 7) |
                   (unsigned)(cz >> 1);
    unsigned off = ((unsigned)(cx & 1) << 2) | ((unsigned)(cy & 1) << 1) |
                   (unsigned)(cz & 1);
    atomicMax(&winner[rank[key] * 8u + off], i);
}

__global__ void scatter_kernel(const float* __restrict__ feats,
                               const int* __restrict__ coords,
                               const unsigned* __restrict__ rank,
                               const int* __restrict__ winner,
                               float* __restrict__ agg, int n) {
    int i = blockIdx.x * blockDim.x + threadIdx.x;
    if (i >= n) return;
    int cx = coords[3 * i], cy = coords[3 * i + 1], cz = coords[3 * i + 2];
    unsigned key = ((unsigned)(cx >> 1) << 14) | ((unsigned)(cy >> 1) << 7) |
                   (unsigned)(cz >> 1);
    unsigned off = ((unsigned)(cx & 1) << 2) | ((unsigned)(cy & 1) << 1) |
                   (unsigned)(cz & 1);
    unsigned r = rank[key];
    if (winner[r * 8u + off] != i) return;
    const float4* src = (const float4*)(feats + (size_t)i * 16);
    float4* dst = (float4*)(agg + (size_t)r * 128u + off * 16u);
    dst[0] = src[0]; dst[1] = src[1]; dst[2] = src[2]; dst[3] = src[3];
}

extern "C" void kernel_launch(void* const* d_in, const int* in_sizes, int n_in,
                              void* d_out, int out_size, void* d_ws, size_t ws_size,
                              hipStream_t stream) {
    const float* feats = (const float*)d_in[0];   // [N,16] f32
    const int* coords  = (const int*)d_in[1];     // [N,3]  i32
    int n = in_sizes[1] / 3;

    float* out        = (float*)d_out;
    float* coords_out = out;                       // [N,3]  (as float; -1 padding)
    float* agg        = out + (size_t)3 * n;       // [N,128]

    // ws layout: presence[CELLS] | rank[CELLS] | blockSums[1024] | winner[8n]
    unsigned* presence  = (unsigned*)d_ws;
    unsigned* rank      = presence + CELLS;
    unsigned* blockSums = rank + CELLS;
    int*      winner    = (int*)(blockSums + 1024);

    hipMemsetAsync(agg, 0, (size_t)128 * n * sizeof(float), stream);
    hipMemsetAsync(presence, 0, (size_t)CELLS * sizeof(unsigned), stream);
    hipMemsetAsync(winner, 0xFF, (size_t)8 * n * sizeof(int), stream);

    fill_coords_kernel<<<(3 * n + 255) / 256, 256, 0, stream>>>(coords_out, 3 * n);
    mark_cells_kernel<<<(n + 255) / 256, 256, 0, stream>>>(coords, presence, n);
    scan1_kernel<<<CELLS / CHUNK, 256, 0, stream>>>(presence, rank, blockSums);
    scan2_kernel<<<1, 512, 0, stream>>>(blockSums);
    finalize_kernel<<<CELLS / 256, 256, 0, stream>>>(presence, rank, blockSums,
                                                     coords_out);
    pick_winner_kernel<<<(n + 255) / 256, 256, 0, stream>>>(coords, rank, winner, n);
    scatter_kernel<<<(n + 255) / 256, 256, 0, stream>>>(feats, coords, rank, winner,
                                                        agg, n);
}

// Round 2
// 376.178 us; speedup vs baseline: 1.0886x; 1.0886x over previous
//
#include <hip/hip_runtime.h>

// Interleaver: coords in [0,256)^3, R=2 -> coarse grid 128^3 = 2^21 cells.
// key = (x>>1)<<14 | (y>>1)<<7 | (z>>1) is the lexicographic row order of
// base = coords//2, so jnp.unique's index = exclusive prefix sum of presence.
// Presence kept as a 2^21-bit bitmap (65536 u32 = 256 KB, L2-resident);
// rank(key) = rank_base[key>>5] + popc(word & below-mask). Duplicate
// (cell,offset) slots resolve last-write-wins => max point index (verified
// absmax=0.0 in R1).

#define WORDS 65536u   // 2^21 / 32

__global__ void mark_kernel(const int* __restrict__ coords,
                            unsigned* __restrict__ bitmap, int n) {
    int i = blockIdx.x * 256 + threadIdx.x;
    if (i >= n) return;
    int cx = coords[3 * i], cy = coords[3 * i + 1], cz = coords[3 * i + 2];
    unsigned key = ((unsigned)(cx >> 1) << 14) | ((unsigned)(cy >> 1) << 7) |
                   (unsigned)(cz >> 1);
    atomicOr(&bitmap[key >> 5], 1u << (key & 31));
}

// 256 blocks x 256 threads: per-chunk popcount totals (chunk = 256 words).
__global__ void chunksum_kernel(const unsigned* __restrict__ bitmap,
                                unsigned* __restrict__ chunkSum) {
    __shared__ unsigned sh[256];
    int t = threadIdx.x;
    sh[t] = __popc(bitmap[blockIdx.x * 256 + t]);
    __syncthreads();
    for (int d = 128; d > 0; d >>= 1) {
        if (t < d) sh[t] += sh[t + d];
        __syncthreads();
    }
    if (t == 0) chunkSum[blockIdx.x] = sh[0];
}

// Single block: exclusive scan of 256 chunk sums; total unique count -> *U.
__global__ void scan_kernel(unsigned* chunkSum, unsigned* U) {
    __shared__ unsigned sh[256];
    int t = threadIdx.x;
    unsigned s = chunkSum[t];
    unsigned x = s;
    sh[t] = x; __syncthreads();
    for (int d = 1; d < 256; d <<= 1) {
        unsigned y = (t >= d) ? sh[t - d] : 0u;
        __syncthreads();
        x += y; sh[t] = x; __syncthreads();
    }
    chunkSum[t] = x - s;
    if (t == 255) *U = x;
}

// rank_base per word + write sorted coarse coords (rows < U).
__global__ void rank_coords_kernel(const unsigned* __restrict__ bitmap,
                                   const unsigned* __restrict__ chunkExcl,
                                   unsigned* __restrict__ rank_base,
                                   float* __restrict__ coords_out) {
    __shared__ unsigned sh[256];
    int t = threadIdx.x;
    unsigned w = blockIdx.x * 256 + t;
    unsigned word = bitmap[w];
    unsigned cnt = __popc(word);
    unsigned x = cnt;
    sh[t] = x; __syncthreads();
    for (int d = 1; d < 256; d <<= 1) {
        unsigned y = (t >= d) ? sh[t - d] : 0u;
        __syncthreads();
        x += y; sh[t] = x; __syncthreads();
    }
    unsigned rb = chunkExcl[blockIdx.x] + x - cnt;
    rank_base[w] = rb;
    while (word) {
        int k = __ffs(word) - 1;
        word &= word - 1;
        unsigned cell = w * 32u + (unsigned)k;
        coords_out[3 * rb + 0] = (float)(cell >> 14);
        coords_out[3 * rb + 1] = (float)((cell >> 7) & 127u);
        coords_out[3 * rb + 2] = (float)(cell & 127u);
        ++rb;
    }
}

// Padding rows (>= U) get fill_value=-1.
__global__ void pad_kernel(const unsigned* __restrict__ U,
                           float* __restrict__ coords_out, int n) {
    int i = blockIdx.x * 256 + threadIdx.x;
    if (i < n && (unsigned)i >= *U) {
        coords_out[3 * i + 0] = -1.0f;
        coords_out[3 * i + 1] = -1.0f;
        coords_out[3 * i + 2] = -1.0f;
    }
}

// Last-write-wins via signed atomicMax on point index (init -1).
__global__ void winner_kernel(const int* __restrict__ coords,
                              const unsigned* __restrict__ bitmap,
                              const unsigned* __restrict__ rank_base,
                              int* __restrict__ winner, int n) {
    int i = blockIdx.x * 256 + threadIdx.x;
    if (i >= n) return;
    int cx = coords[3 * i], cy = coords[3 * i + 1], cz = coords[3 * i + 2];
    unsigned key = ((unsigned)(cx >> 1) << 14) | ((unsigned)(cy >> 1) << 7) |
                   (unsigned)(cz >> 1);
    unsigned off = ((unsigned)(cx & 1) << 2) | ((unsigned)(cy & 1) << 1) |
                   (unsigned)(cz & 1);
    unsigned wd = key >> 5;
    unsigned r = rank_base[wd] + __popc(bitmap[wd] & ((1u << (key & 31)) - 1u));
    atomicMax(&winner[r * 8u + off], i);
}

// Write the ENTIRE agg exactly once, coalesced float4 (no pre-memset).
__global__ void gather_kernel(const float* __restrict__ feats,
                              const int* __restrict__ winner,
                              float* __restrict__ agg, int total4) {
    int j = blockIdx.x * 256 + threadIdx.x;   // one float4 per thread
    if (j >= total4) return;
    int slot = j >> 2;                        // (row*8 + off)
    int c4 = j & 3;
    int w = winner[slot];
    float4 v = make_float4(0.f, 0.f, 0.f, 0.f);
    if (w >= 0) v = ((const float4*)feats)[(size_t)w * 4 + c4];
    ((float4*)agg)[j] = v;
}

extern "C" void kernel_launch(void* const* d_in, const int* in_sizes, int n_in,
                              void* d_out, int out_size, void* d_ws, size_t ws_size,
                              hipStream_t stream) {
    const float* feats = (const float*)d_in[0];   // [N,16] f32
    const int* coords  = (const int*)d_in[1];     // [N,3]  i32
    int n = in_sizes[1] / 3;

    float* out        = (float*)d_out;
    float* coords_out = out;                      // [N,3]  (floats; -1 padding)
    float* agg        = out + (size_t)3 * n;      // [N,128]

    // ws: bitmap[65536] | rank_base[65536] | chunkSum[256] | U[1] | winner[8n]
    unsigned* bitmap    = (unsigned*)d_ws;
    unsigned* rank_base = bitmap + WORDS;
    unsigned* chunkSum  = rank_base + WORDS;
    unsigned* U         = chunkSum + 256;
    int*      winner    = (int*)(U + 4);          // keep 16B alignment

    hipMemsetAsync(bitmap, 0, WORDS * sizeof(unsigned), stream);
    hipMemsetAsync(winner, 0xFF, (size_t)8 * n * sizeof(int), stream);

    int nb = (n + 255) / 256;
    mark_kernel<<<nb, 256, 0, stream>>>(coords, bitmap, n);
    chunksum_kernel<<<WORDS / 256, 256, 0, stream>>>(bitmap, chunkSum);
    scan_kernel<<<1, 256, 0, stream>>>(chunkSum, U);
    rank_coords_kernel<<<WORDS / 256, 256, 0, stream>>>(bitmap, chunkSum,
                                                        rank_base, coords_out);
    pad_kernel<<<nb, 256, 0, stream>>>(U, coords_out, n);
    winner_kernel<<<nb, 256, 0, stream>>>(coords, bitmap, rank_base, winner, n);
    int total4 = n * 32;                          // n*128 floats / 4
    gather_kernel<<<(total4 + 255) / 256, 256, 0, stream>>>(feats, winner, agg,
                                                            total4);
}

// Round 4
// 372.192 us; speedup vs baseline: 1.1002x; 1.0107x over previous
//
#include <hip/hip_runtime.h>

// Interleaver: coords in [0,256)^3, R=2 -> coarse grid 128^3 = 2^21 cells.
// key = (x>>1)<<14 | (y>>1)<<7 | (z>>1) is the lexicographic row order of
// base = coords//2, so jnp.unique's index = exclusive prefix sum of presence.
// Presence: 2^21-bit bitmap (65536 u32 = 256 KB, L2-resident);
// rank(key) = rank_base[key>>5] + popc(word & below-mask). Duplicate
// (cell,offset) slots resolve last-write-wins => max point index (absmax=0.0
// verified R1/R2).
//
// R4 = R3 with the NT-store type fixed: __builtin_nontemporal_store needs a
// clang ext_vector_type, not HIP's float4 class.

#define WORDS 65536u   // 2^21 / 32

typedef float v4f __attribute__((ext_vector_type(4)));

// mark presence bits + grid-stride init winner[8n] = -1 (independent arrays).
__global__ void mark_init_kernel(const int* __restrict__ coords,
                                 unsigned* __restrict__ bitmap,
                                 int* __restrict__ winner, int n) {
    int i = blockIdx.x * 256 + threadIdx.x;
    int nthreads = gridDim.x * 256;
    for (int s = i; s < 8 * n; s += nthreads) winner[s] = -1;
    if (i >= n) return;
    int cx = coords[3 * i], cy = coords[3 * i + 1], cz = coords[3 * i + 2];
    unsigned key = ((unsigned)(cx >> 1) << 14) | ((unsigned)(cy >> 1) << 7) |
                   (unsigned)(cz >> 1);
    atomicOr(&bitmap[key >> 5], 1u << (key & 31));
}

// Single block: per-256-word-chunk popcount sums + exclusive scan -> chunkExcl,
// total unique count -> *U.
__global__ void scanall_kernel(const unsigned* __restrict__ bitmap,
                               unsigned* __restrict__ chunkExcl,
                               unsigned* __restrict__ U) {
    __shared__ unsigned sh[256];
    int t = threadIdx.x;
    unsigned s = 0;
    unsigned base = (unsigned)t * 256u;
#pragma unroll 8
    for (unsigned j = 0; j < 256u; ++j) s += __popc(bitmap[base + j]);
    unsigned x = s;
    sh[t] = x; __syncthreads();
    for (int d = 1; d < 256; d <<= 1) {
        unsigned y = (t >= d) ? sh[t - d] : 0u;
        __syncthreads();
        x += y; sh[t] = x; __syncthreads();
    }
    chunkExcl[t] = x - s;
    if (t == 255) *U = x;
}

// rank_base per word + sorted coarse coords (rows < U) + pad tail (rows >= U).
__global__ void rank_coords_pad_kernel(const unsigned* __restrict__ bitmap,
                                       const unsigned* __restrict__ chunkExcl,
                                       const unsigned* __restrict__ U,
                                       unsigned* __restrict__ rank_base,
                                       float* __restrict__ coords_out, int n) {
    __shared__ unsigned sh[256];
    int t = threadIdx.x;
    unsigned w = blockIdx.x * 256 + t;
    unsigned word = bitmap[w];
    unsigned cnt = __popc(word);
    unsigned x = cnt;
    sh[t] = x; __syncthreads();
    for (int d = 1; d < 256; d <<= 1) {
        unsigned y = (t >= d) ? sh[t - d] : 0u;
        __syncthreads();
        x += y; sh[t] = x; __syncthreads();
    }
    unsigned rb = chunkExcl[blockIdx.x] + x - cnt;
    rank_base[w] = rb;
    while (word) {
        int k = __ffs(word) - 1;
        word &= word - 1;
        unsigned cell = w * 32u + (unsigned)k;
        coords_out[3 * rb + 0] = (float)(cell >> 14);
        coords_out[3 * rb + 1] = (float)((cell >> 7) & 127u);
        coords_out[3 * rb + 2] = (float)(cell & 127u);
        ++rb;
    }
    // pad: rows in [U, n) get fill_value=-1 (grid-stride over 65536 threads)
    unsigned u = *U;
    int nthreads = gridDim.x * 256;
    for (unsigned i = u + w; i < (unsigned)n; i += nthreads) {
        coords_out[3 * i + 0] = -1.0f;
        coords_out[3 * i + 1] = -1.0f;
        coords_out[3 * i + 2] = -1.0f;
    }
}

// Last-write-wins via signed atomicMax on point index (init -1 in mark).
__global__ void winner_kernel(const int* __restrict__ coords,
                              const unsigned* __restrict__ bitmap,
                              const unsigned* __restrict__ rank_base,
                              int* __restrict__ winner, int n) {
    int i = blockIdx.x * 256 + threadIdx.x;
    if (i >= n) return;
    int cx = coords[3 * i], cy = coords[3 * i + 1], cz = coords[3 * i + 2];
    unsigned key = ((unsigned)(cx >> 1) << 14) | ((unsigned)(cy >> 1) << 7) |
                   (unsigned)(cz >> 1);
    unsigned off = ((unsigned)(cx & 1) << 2) | ((unsigned)(cy & 1) << 1) |
                   (unsigned)(cz & 1);
    unsigned wd = key >> 5;
    unsigned r = rank_base[wd] + __popc(bitmap[wd] & ((1u << (key & 31)) - 1u));
    atomicMax(&winner[r * 8u + off], i);
}

// Write the ENTIRE agg exactly once, coalesced float4, nontemporal stream.
__global__ void gather_kernel(const float* __restrict__ feats,
                              const int* __restrict__ winner,
                              float* __restrict__ agg, int total4) {
    int j = blockIdx.x * 256 + threadIdx.x;   // one float4 per thread
    if (j >= total4) return;
    int slot = j >> 2;                        // (row*8 + off)
    int c4 = j & 3;
    int w = __builtin_nontemporal_load(&winner[slot]);
    v4f v = (v4f)(0.f);
    if (w >= 0) v = ((const v4f*)feats)[(size_t)w * 4 + c4];
    __builtin_nontemporal_store(v, (v4f*)agg + j);
}

extern "C" void kernel_launch(void* const* d_in, const int* in_sizes, int n_in,
                              void* d_out, int out_size, void* d_ws, size_t ws_size,
                              hipStream_t stream) {
    const float* feats = (const float*)d_in[0];   // [N,16] f32
    const int* coords  = (const int*)d_in[1];     // [N,3]  i32
    int n = in_sizes[1] / 3;

    float* out        = (float*)d_out;
    float* coords_out = out;                      // [N,3]  (floats; -1 padding)
    float* agg        = out + (size_t)3 * n;      // [N,128]

    // ws: bitmap[65536] | rank_base[65536] | chunkExcl[256] | U[1] | winner[8n]
    unsigned* bitmap    = (unsigned*)d_ws;
    unsigned* rank_base = bitmap + WORDS;
    unsigned* chunkExcl = rank_base + WORDS;
    unsigned* U         = chunkExcl + 256;
    int*      winner    = (int*)(U + 4);          // keep 16B alignment

    (void)hipMemsetAsync(bitmap, 0, WORDS * sizeof(unsigned), stream);

    int nb = (n + 255) / 256;
    mark_init_kernel<<<nb, 256, 0, stream>>>(coords, bitmap, winner, n);
    scanall_kernel<<<1, 256, 0, stream>>>(bitmap, chunkExcl, U);
    rank_coords_pad_kernel<<<WORDS / 256, 256, 0, stream>>>(bitmap, chunkExcl, U,
                                                            rank_base, coords_out, n);
    winner_kernel<<<nb, 256, 0, stream>>>(coords, bitmap, rank_base, winner, n);
    int total4 = n * 32;                          // n*128 floats / 4
    gather_kernel<<<(total4 + 255) / 256, 256, 0, stream>>>(feats, winner, agg,
                                                            total4);
}